// Round 1
// 1089.696 us; speedup vs baseline: 1.1084x; 1.1084x over previous
//
#include <hip/hip_runtime.h>

// CATSCluster: fused 3-stream MLP (768->256->128) + combine on MI355X.
// Round N+1: latency/occupancy attack.
//  - 512-thread blocks (8 waves), 64-row tile -> 2 blocks/CU = 4 waves/SIMD
//    (was 2 waves/SIMD). __launch_bounds__(512,4) caps VGPR at 128.
//  - 2-chunk-deep X prefetch: global load for chunk c+2 issues at top of
//    chunk c; split/LDS-write of c+1 consumes data loaded a full chunk ago,
//    hiding ~900cy HBM latency (T14 issue-early/write-late).
//  - stream order p1,p2,q: only |zp1-zp2| (16 VGPRs) lives across streams
//    (was 96 VGPRs of z[3][4][2]); q's GEMM2 feeds the W5 dot directly.
// Numerics unchanged: split-precision bf16 MFMA, 3 terms (hh+hl+lh) GEMM1,
// 2 terms GEMM2, fp32 combine.

typedef short short8 __attribute__((ext_vector_type(8)));   // 8 x bf16 (4 VGPRs)
typedef float f32x4 __attribute__((ext_vector_type(4)));    // MFMA accumulator

// d_ws layout (in unsigned short elements)
#define W1H_OFF 0u
#define W1L_OFF 196608u
#define W3H_OFF 393216u
#define W3L_OFF 589824u
#define W2H_OFF 786432u
#define W2L_OFF 819200u
#define W4H_OFF 851968u
#define W4L_OFF 884736u
// total: 917504 shorts = 1,835,008 bytes of d_ws

__device__ __forceinline__ unsigned short bf16_rne(float f) {
  unsigned int u = __float_as_uint(f);
  u += 0x7FFFu + ((u >> 16) & 1u);      // round-to-nearest-even
  return (unsigned short)(u >> 16);
}

__device__ __forceinline__ void split_bf16(float f, unsigned short& h, unsigned short& l) {
  h = bf16_rne(f);
  float fh = __uint_as_float(((unsigned int)h) << 16);
  l = bf16_rne(f - fh);                 // residual; |x - hi - lo| ~ 2^-18 |x|
}

__global__ __launch_bounds__(256) void prep_weights(
    const float* __restrict__ W1, const float* __restrict__ W2,
    const float* __restrict__ W3, const float* __restrict__ W4,
    unsigned short* __restrict__ ws)
{
  int i = blockIdx.x * 256 + threadIdx.x;
  if (i < 196608) {
    unsigned short h, l;
    split_bf16(W1[i], h, l); ws[W1H_OFF + i] = h; ws[W1L_OFF + i] = l;
    split_bf16(W3[i], h, l); ws[W3H_OFF + i] = h; ws[W3L_OFF + i] = l;
    if (i < 32768) {
      split_bf16(W2[i], h, l); ws[W2H_OFF + i] = h; ws[W2L_OFF + i] = l;
      split_bf16(W4[i], h, l); ws[W4H_OFF + i] = h; ws[W4L_OFF + i] = l;
    }
  }
}

#define STRIDE_A 40    // shorts per A-row in LDS (32 used; 80B stride -> 16B aligned, 2-way banks = free)
#define STRIDE_H 264   // shorts per H-row in LDS (256 used; 528B stride -> 16B aligned, 2-way banks = free)

__global__ __launch_bounds__(512, 4) void catsc_main(
    const float* __restrict__ X, const unsigned short* __restrict__ ws,
    const float* __restrict__ W5, float* __restrict__ out)
{
  __shared__ short lsA[2][2][64 * STRIDE_A];  // [dbuf][hi/lo][row*40+k]  20,480 B
  __shared__ short lsH[64 * STRIDE_H];        // relu(h) as bf16          33,792 B
  __shared__ float lsPart[8][64];             // cross-wave dot partials   2,048 B
                                              // total 56,320 B -> 2 blocks/CU

  const int tid  = threadIdx.x;
  const int wave = tid >> 6;      // 0..7
  const int lane = tid & 63;
  const int l15  = lane & 15;
  const int q    = lane >> 4;     // quad index 0..3
  const int blk  = blockIdx.x;    // 0..1023, 64 rows each; 64 blocks per n (4096/64)

  // X_data is (16, 4097, 2304); skip row 0 of each n.
  const float* Xb = X + (size_t)((blk >> 6) * 4097 + 1 + ((blk & 63) << 6)) * 2304;

  // cooperative staging coords: thread -> (row, 4-float segment); 512 thr cover 64x32 in one shot
  const int srow = tid >> 3;        // 0..63
  const int f4   = (tid & 7) << 2;  // float offset 0,4,...,28 within 32-col chunk

  f32x4 zp[4];   // after p1: zp1 ; after p2: |zp1 - zp2| ; consumed by q-combine

#pragma unroll
  for (int s = 0; s < 3; ++s) {
    // stream order: s=0 -> p1 (cols 768..), s=1 -> p2 (cols 1536..), s=2 -> q (cols 0..)
    const int so = (s == 0) ? 768 : (s == 1) ? 1536 : 0;
    const unsigned short* B1h = ws + (s == 2 ? W3H_OFF : W1H_OFF);
    const unsigned short* B1l = ws + (s == 2 ? W3L_OFF : W1L_OFF);
    const unsigned short* B2h = ws + (s == 2 ? W4H_OFF : W2H_OFF);
    const unsigned short* B2l = ws + (s == 2 ? W4L_OFF : W2L_OFF);

    const float* Xrow = Xb + (size_t)srow * 2304 + so + f4;

    f32x4 acc[4][2];
#pragma unroll
    for (int m = 0; m < 4; ++m)
#pragma unroll
      for (int n = 0; n < 2; ++n)
        acc[m][n] = f32x4{0.f, 0.f, 0.f, 0.f};

    // ---- prologue: stage chunk 0 now; preload chunk 1 into regs ----
    {
      float4 v0 = *(const float4*)(Xrow);
      unsigned short h0,h1,h2,h3,l0,l1,l2,l3;
      split_bf16(v0.x,h0,l0); split_bf16(v0.y,h1,l1);
      split_bf16(v0.z,h2,l2); split_bf16(v0.w,h3,l3);
      uint2 ph, pl;
      ph.x = (unsigned)h0 | ((unsigned)h1 << 16); ph.y = (unsigned)h2 | ((unsigned)h3 << 16);
      pl.x = (unsigned)l0 | ((unsigned)l1 << 16); pl.y = (unsigned)l2 | ((unsigned)l3 << 16);
      *(uint2*)&lsA[0][0][srow * STRIDE_A + f4] = ph;
      *(uint2*)&lsA[0][1][srow * STRIDE_A + f4] = pl;
    }
    float4 vB = *(const float4*)(Xrow + 32);   // chunk 1, split during c=0
    __syncthreads();

    // ---- GEMM1 K-loop: 24 chunks of K=32, LDS double-buffered,
    //      X loads pipelined two chunks deep ----
    for (int c = 0; c < 24; ++c) {
      const int b = c & 1;

      // issue X loads for chunk c+2 first (clamped; tail re-loads hit L2)
      const int cl = (c + 2 < 24) ? (c + 2) : 23;
      float4 vN = *(const float4*)(Xrow + cl * 32);

      // B fragments (weights, bf16 hi/lo) straight from L2.
      // lane needs W[n = (wave*2+nt)*16 + l15][k = c*32 + q*8 + j]
      short8 Bh[2], Bl[2];
#pragma unroll
      for (int n = 0; n < 2; ++n) {
        size_t off = (size_t)((wave * 2 + n) * 16 + l15) * 768 + c * 32 + q * 8;
        Bh[n] = *(const short8*)(B1h + off);
        Bl[n] = *(const short8*)(B1l + off);
      }
      // A fragments from LDS: A[m = mt*16 + l15][k = q*8 + j]
      short8 Ah[4], Al[4];
#pragma unroll
      for (int m = 0; m < 4; ++m) {
        int a = (m * 16 + l15) * STRIDE_A + q * 8;
        Ah[m] = *(const short8*)&lsA[b][0][a];
        Al[m] = *(const short8*)&lsA[b][1][a];
      }

      // split the reg-staged chunk c+1 (loaded a full chunk ago) into the
      // other LDS buffer — VALU work here also covers the ds_read/B-load latency
      if (c + 1 < 24) {
        unsigned short h0,h1,h2,h3,l0,l1,l2,l3;
        split_bf16(vB.x,h0,l0); split_bf16(vB.y,h1,l1);
        split_bf16(vB.z,h2,l2); split_bf16(vB.w,h3,l3);
        uint2 ph, pl;
        ph.x = (unsigned)h0 | ((unsigned)h1 << 16); ph.y = (unsigned)h2 | ((unsigned)h3 << 16);
        pl.x = (unsigned)l0 | ((unsigned)l1 << 16); pl.y = (unsigned)l2 | ((unsigned)l3 << 16);
        const int wb = b ^ 1;
        *(uint2*)&lsA[wb][0][srow * STRIDE_A + f4] = ph;
        *(uint2*)&lsA[wb][1][srow * STRIDE_A + f4] = pl;
      }

      // 3-term split product; term-major keeps same-acc MFMAs 8 apart
#pragma unroll
      for (int m = 0; m < 4; ++m)
#pragma unroll
        for (int n = 0; n < 2; ++n)
          acc[m][n] = __builtin_amdgcn_mfma_f32_16x16x32_bf16(Ah[m], Bh[n], acc[m][n], 0, 0, 0);
#pragma unroll
      for (int m = 0; m < 4; ++m)
#pragma unroll
        for (int n = 0; n < 2; ++n)
          acc[m][n] = __builtin_amdgcn_mfma_f32_16x16x32_bf16(Ah[m], Bl[n], acc[m][n], 0, 0, 0);
#pragma unroll
      for (int m = 0; m < 4; ++m)
#pragma unroll
        for (int n = 0; n < 2; ++n)
          acc[m][n] = __builtin_amdgcn_mfma_f32_16x16x32_bf16(Al[m], Bh[n], acc[m][n], 0, 0, 0);

      __syncthreads();
      vB = vN;
    }

    // ---- H = relu(acc) -> LDS as bf16 (C-layout: col=l15, row=q*4+i) ----
#pragma unroll
    for (int m = 0; m < 4; ++m)
#pragma unroll
      for (int n = 0; n < 2; ++n) {
        int col = (wave * 2 + n) * 16 + l15;
#pragma unroll
        for (int i = 0; i < 4; ++i) {
          int row = m * 16 + q * 4 + i;
          lsH[row * STRIDE_H + col] = bf16_rne(fmaxf(acc[m][n][i], 0.f));
        }
      }
    __syncthreads();

    // ---- GEMM2: (64 x 256) x (256 -> 128), H bf16 x W split (2 terms);
    //      8 waves x 16 output cols each ----
    f32x4 acc2[4];
#pragma unroll
    for (int m = 0; m < 4; ++m) acc2[m] = f32x4{0.f, 0.f, 0.f, 0.f};

    for (int c2 = 0; c2 < 8; ++c2) {
      size_t off = (size_t)(wave * 16 + l15) * 256 + c2 * 32 + q * 8;
      short8 Ch = *(const short8*)(B2h + off);
      short8 Cl = *(const short8*)(B2l + off);
      short8 Ha[4];
#pragma unroll
      for (int m = 0; m < 4; ++m)
        Ha[m] = *(const short8*)&lsH[(m * 16 + l15) * STRIDE_H + c2 * 32 + q * 8];
#pragma unroll
      for (int m = 0; m < 4; ++m)
        acc2[m] = __builtin_amdgcn_mfma_f32_16x16x32_bf16(Ha[m], Ch, acc2[m], 0, 0, 0);
#pragma unroll
      for (int m = 0; m < 4; ++m)
        acc2[m] = __builtin_amdgcn_mfma_f32_16x16x32_bf16(Ha[m], Cl, acc2[m], 0, 0, 0);
    }

    // ---- per-stream epilogue: minimal cross-stream register state ----
    if (s == 0) {                       // zp1
#pragma unroll
      for (int m = 0; m < 4; ++m)
#pragma unroll
        for (int i = 0; i < 4; ++i)
          zp[m][i] = fmaxf(acc2[m][i], 0.f);
    } else if (s == 1) {                // |zp1 - zp2|
#pragma unroll
      for (int m = 0; m < 4; ++m)
#pragma unroll
        for (int i = 0; i < 4; ++i)
          zp[m][i] = fabsf(zp[m][i] - fmaxf(acc2[m][i], 0.f));
    } else {                            // q: combine + W5 dot immediately
      const float w5c = W5[wave * 16 + l15];
#pragma unroll
      for (int m = 0; m < 4; ++m)
#pragma unroll
        for (int i = 0; i < 4; ++i) {
          float v = fmaxf(acc2[m][i], 0.f) * zp[m][i] * w5c;
          // reduce over the 16 cols held by l15 (within each quad group)
          v += __shfl_xor(v, 1);
          v += __shfl_xor(v, 2);
          v += __shfl_xor(v, 4);
          v += __shfl_xor(v, 8);
          if (l15 == 0) lsPart[wave][m * 16 + q * 4 + i] = v;
        }
    }
    // No barrier needed between GEMM2(s) and lsA prologue writes of s+1:
    // disjoint LDS regions; lsH(s+1) writes are behind 25+ collective barriers.
  }

  __syncthreads();
  if (tid < 64) {
    float sum = lsPart[0][tid] + lsPart[1][tid] + lsPart[2][tid] + lsPart[3][tid]
              + lsPart[4][tid] + lsPart[5][tid] + lsPart[6][tid] + lsPart[7][tid];
    out[(size_t)blk * 64 + tid] = tanhf(fmaxf(sum, 0.f));
  }
}

extern "C" void kernel_launch(void* const* d_in, const int* in_sizes, int n_in,
                              void* d_out, int out_size, void* d_ws, size_t ws_size,
                              hipStream_t stream) {
  const float* X  = (const float*)d_in[0];
  const float* W1 = (const float*)d_in[1];
  const float* W2 = (const float*)d_in[2];
  const float* W3 = (const float*)d_in[3];
  const float* W4 = (const float*)d_in[4];
  const float* W5 = (const float*)d_in[5];
  float* out = (float*)d_out;
  unsigned short* ws = (unsigned short*)d_ws;  // needs 1.75 MB

  prep_weights<<<dim3(768), dim3(256), 0, stream>>>(W1, W2, W3, W4, ws);
  catsc_main<<<dim3(1024), dim3(512), 0, stream>>>(X, ws, W5, out);
}

// Round 2
// 1061.836 us; speedup vs baseline: 1.1375x; 1.0262x over previous
//
#include <hip/hip_runtime.h>

// CATSCluster: fused 3-stream MLP (768->256->128) + combine on MI355X.
// Round N+2: kill spills + halve barrier count.
//  - K=64 per barrier interval (12 intervals/stream, was 24 chunks): each
//    __syncthreads drains vmcnt(0), so the prefetch can only hide latency
//    within one interval -> make the interval longer (~1000cy of MFMA+VALU
//    covers ~900cy HBM latency).
//  - depth-1 reg prefetch: X for interval p+1 issued at TOP of interval p,
//    split+written to the other LDS buffer at its END, just before barrier.
//  - arch-VGPR diet (round1 spilled 86MB scratch: AGPR=64 forced arch=64):
//    A-frags in m-pairs (16 regs), B-frags per K=32 sub-chunk (16 regs),
//    single 8-reg X buffer. Target arch ~70 + AGPR ~48..64 <= 128 cap.
// Numerics unchanged: split-precision bf16 MFMA, 3 terms (hh+hl+lh) GEMM1,
// 2 terms GEMM2, fp32 combine.

typedef short short8 __attribute__((ext_vector_type(8)));   // 8 x bf16 (4 VGPRs)
typedef float f32x4 __attribute__((ext_vector_type(4)));    // MFMA accumulator

// d_ws layout (in unsigned short elements)
#define W1H_OFF 0u
#define W1L_OFF 196608u
#define W3H_OFF 393216u
#define W3L_OFF 589824u
#define W2H_OFF 786432u
#define W2L_OFF 819200u
#define W4H_OFF 851968u
#define W4L_OFF 884736u
// total: 917504 shorts = 1,835,008 bytes of d_ws

__device__ __forceinline__ unsigned short bf16_rne(float f) {
  unsigned int u = __float_as_uint(f);
  u += 0x7FFFu + ((u >> 16) & 1u);      // round-to-nearest-even
  return (unsigned short)(u >> 16);
}

__device__ __forceinline__ void split_bf16(float f, unsigned short& h, unsigned short& l) {
  h = bf16_rne(f);
  float fh = __uint_as_float(((unsigned int)h) << 16);
  l = bf16_rne(f - fh);                 // residual; |x - hi - lo| ~ 2^-18 |x|
}

__device__ __forceinline__ void pack_split4(const float4 v, uint2& ph, uint2& pl) {
  unsigned short h0,h1,h2,h3,l0,l1,l2,l3;
  split_bf16(v.x,h0,l0); split_bf16(v.y,h1,l1);
  split_bf16(v.z,h2,l2); split_bf16(v.w,h3,l3);
  ph.x = (unsigned)h0 | ((unsigned)h1 << 16); ph.y = (unsigned)h2 | ((unsigned)h3 << 16);
  pl.x = (unsigned)l0 | ((unsigned)l1 << 16); pl.y = (unsigned)l2 | ((unsigned)l3 << 16);
}

__global__ __launch_bounds__(256) void prep_weights(
    const float* __restrict__ W1, const float* __restrict__ W2,
    const float* __restrict__ W3, const float* __restrict__ W4,
    unsigned short* __restrict__ ws)
{
  int i = blockIdx.x * 256 + threadIdx.x;
  if (i < 196608) {
    unsigned short h, l;
    split_bf16(W1[i], h, l); ws[W1H_OFF + i] = h; ws[W1L_OFF + i] = l;
    split_bf16(W3[i], h, l); ws[W3H_OFF + i] = h; ws[W3L_OFF + i] = l;
    if (i < 32768) {
      split_bf16(W2[i], h, l); ws[W2H_OFF + i] = h; ws[W2L_OFF + i] = l;
      split_bf16(W4[i], h, l); ws[W4H_OFF + i] = h; ws[W4L_OFF + i] = l;
    }
  }
}

#define STRIDE_A 72    // shorts per A-row in LDS (64 used; 144B stride, 16B-aligned)
#define STRIDE_H 264   // shorts per H-row in LDS (256 used; 528B stride, 16B-aligned)

__global__ __launch_bounds__(512, 4) void catsc_main(
    const float* __restrict__ X, const unsigned short* __restrict__ ws,
    const float* __restrict__ W5, float* __restrict__ out)
{
  __shared__ short lsA[2][2][64 * STRIDE_A]; // [dbuf][hi/lo][row*72+k]  36,864 B
  __shared__ short lsH[64 * STRIDE_H];       // relu(h) as bf16          33,792 B
  __shared__ float lsPart[8][64];            // cross-wave dot partials   2,048 B
                                             // total 72,704 B -> 2 blocks/CU

  const int tid  = threadIdx.x;
  const int wave = tid >> 6;      // 0..7
  const int lane = tid & 63;
  const int l15  = lane & 15;
  const int q    = lane >> 4;     // quad index 0..3
  const int blk  = blockIdx.x;    // 0..1023, 64 rows each; 64 blocks per n (4096/64)

  // X_data is (16, 4097, 2304); skip row 0 of each n.
  const float* Xb = X + (size_t)((blk >> 6) * 4097 + 1 + ((blk & 63) << 6)) * 2304;

  // cooperative staging coords: thread -> (row, 8-float segment); 512 thr cover 64x64/interval
  const int srow = tid >> 3;        // 0..63
  const int scol = (tid & 7) << 3;  // float offset 0,8,...,56 within 64-col interval
  const float* Xs = Xb + (size_t)srow * 2304 + scol;
  short* lsW = &lsA[0][0][0];       // raw base for staging writes
  const int sidx = srow * STRIDE_A + scol;   // short index within one lsA plane
  const int PLANE = 64 * STRIDE_A;           // shorts per [hi/lo] plane

  f32x4 zp[4];   // after p1: zp1 ; after p2: |zp1 - zp2| ; consumed by q-combine

  // T14: interval-0 X data for stream 0 (p1, cols 768..) issued at kernel top
  float4 vP0 = *(const float4*)(Xs + 768);
  float4 vP1 = *(const float4*)(Xs + 768 + 4);

#pragma unroll
  for (int s = 0; s < 3; ++s) {
    // stream order: s=0 -> p1 (768..), s=1 -> p2 (1536..), s=2 -> q (0..)
    const int so = (s == 0) ? 768 : (s == 1) ? 1536 : 0;
    const unsigned short* B1h = ws + (s == 2 ? W3H_OFF : W1H_OFF);
    const unsigned short* B1l = ws + (s == 2 ? W3L_OFF : W1L_OFF);
    const unsigned short* B2h = ws + (s == 2 ? W4H_OFF : W2H_OFF);
    const unsigned short* B2l = ws + (s == 2 ? W4L_OFF : W2L_OFF);

    f32x4 acc[4][2];
#pragma unroll
    for (int m = 0; m < 4; ++m)
#pragma unroll
      for (int n = 0; n < 2; ++n)
        acc[m][n] = f32x4{0.f, 0.f, 0.f, 0.f};

    // ---- prologue: stage interval 0 (from the early-issued vP regs) ----
    {
      uint2 ph, pl;
      pack_split4(vP0, ph, pl);
      *(uint2*)&lsW[sidx]         = ph;
      *(uint2*)&lsW[PLANE + sidx] = pl;
      pack_split4(vP1, ph, pl);
      *(uint2*)&lsW[sidx + 4]         = ph;
      *(uint2*)&lsW[PLANE + sidx + 4] = pl;
    }
    __syncthreads();

    // ---- GEMM1: 12 intervals of K=64, double-buffered, depth-1 prefetch ----
    for (int p = 0; p < 12; ++p) {
      const int b = p & 1;
      // issue X loads for interval p+1 now; consumed at end of this interval
      float4 vB0, vB1;
      if (p + 1 < 12) {
        vB0 = *(const float4*)(Xs + so + (p + 1) * 64);
        vB1 = *(const float4*)(Xs + so + (p + 1) * 64 + 4);
      }

#pragma unroll
      for (int sub = 0; sub < 2; ++sub) {
        // B fragments (weights, bf16 hi/lo) from L2, per K=32 sub-chunk.
        // lane needs W[n = (wave*2+nt)*16 + l15][k = p*64 + sub*32 + q*8 + j]
        short8 Bh[2], Bl[2];
#pragma unroll
        for (int n = 0; n < 2; ++n) {
          size_t off = (size_t)((wave * 2 + n) * 16 + l15) * 768 + p * 64 + sub * 32 + q * 8;
          Bh[n] = *(const short8*)(B1h + off);
          Bl[n] = *(const short8*)(B1l + off);
        }
        // A fragments from LDS in m-pairs (16 regs live instead of 32)
#pragma unroll
        for (int mh = 0; mh < 2; ++mh) {
          short8 Ah[2], Al[2];
#pragma unroll
          for (int mm = 0; mm < 2; ++mm) {
            int a = ((mh * 2 + mm) * 16 + l15) * STRIDE_A + sub * 32 + q * 8;
            Ah[mm] = *(const short8*)&lsA[b][0][a];
            Al[mm] = *(const short8*)&lsA[b][1][a];
          }
          // 12 MFMAs, term-major: same-acc spacing = 4
#pragma unroll
          for (int mm = 0; mm < 2; ++mm)
#pragma unroll
            for (int n = 0; n < 2; ++n)
              acc[mh*2+mm][n] = __builtin_amdgcn_mfma_f32_16x16x32_bf16(Ah[mm], Bh[n], acc[mh*2+mm][n], 0, 0, 0);
#pragma unroll
          for (int mm = 0; mm < 2; ++mm)
#pragma unroll
            for (int n = 0; n < 2; ++n)
              acc[mh*2+mm][n] = __builtin_amdgcn_mfma_f32_16x16x32_bf16(Ah[mm], Bl[n], acc[mh*2+mm][n], 0, 0, 0);
#pragma unroll
          for (int mm = 0; mm < 2; ++mm)
#pragma unroll
            for (int n = 0; n < 2; ++n)
              acc[mh*2+mm][n] = __builtin_amdgcn_mfma_f32_16x16x32_bf16(Al[mm], Bh[n], acc[mh*2+mm][n], 0, 0, 0);
        }
      }

      // split the prefetched interval p+1 into the other LDS buffer
      if (p + 1 < 12) {
        const int wb = b ^ 1;
        short* dst = &lsA[wb][0][0];
        uint2 ph, pl;
        pack_split4(vB0, ph, pl);
        *(uint2*)&dst[sidx]         = ph;
        *(uint2*)&dst[PLANE + sidx] = pl;
        pack_split4(vB1, ph, pl);
        *(uint2*)&dst[sidx + 4]         = ph;
        *(uint2*)&dst[PLANE + sidx + 4] = pl;
      }
      __syncthreads();
    }

    // ---- H = relu(acc) -> LDS as bf16 (C-layout: col=l15, row=q*4+i) ----
#pragma unroll
    for (int m = 0; m < 4; ++m)
#pragma unroll
      for (int n = 0; n < 2; ++n) {
        int col = (wave * 2 + n) * 16 + l15;
#pragma unroll
        for (int i = 0; i < 4; ++i) {
          int row = m * 16 + q * 4 + i;
          lsH[row * STRIDE_H + col] = bf16_rne(fmaxf(acc[m][n][i], 0.f));
        }
      }
    __syncthreads();

    // T14: issue next stream's interval-0 X loads now; consumed after GEMM2
    if (s == 0) {
      vP0 = *(const float4*)(Xs + 1536);
      vP1 = *(const float4*)(Xs + 1536 + 4);
    } else if (s == 1) {
      vP0 = *(const float4*)(Xs);
      vP1 = *(const float4*)(Xs + 4);
    }

    // ---- GEMM2: (64 x 256) x (256 -> 128), H bf16 x W split (2 terms);
    //      8 waves x 16 output cols each ----
    f32x4 acc2[4];
#pragma unroll
    for (int m = 0; m < 4; ++m) acc2[m] = f32x4{0.f, 0.f, 0.f, 0.f};

    for (int c2 = 0; c2 < 8; ++c2) {
      size_t off = (size_t)(wave * 16 + l15) * 256 + c2 * 32 + q * 8;
      short8 Ch = *(const short8*)(B2h + off);
      short8 Cl = *(const short8*)(B2l + off);
      short8 Ha[4];
#pragma unroll
      for (int m = 0; m < 4; ++m)
        Ha[m] = *(const short8*)&lsH[(m * 16 + l15) * STRIDE_H + c2 * 32 + q * 8];
#pragma unroll
      for (int m = 0; m < 4; ++m)
        acc2[m] = __builtin_amdgcn_mfma_f32_16x16x32_bf16(Ha[m], Ch, acc2[m], 0, 0, 0);
#pragma unroll
      for (int m = 0; m < 4; ++m)
        acc2[m] = __builtin_amdgcn_mfma_f32_16x16x32_bf16(Ha[m], Cl, acc2[m], 0, 0, 0);
    }

    // ---- per-stream epilogue: minimal cross-stream register state ----
    if (s == 0) {                       // zp1
#pragma unroll
      for (int m = 0; m < 4; ++m)
#pragma unroll
        for (int i = 0; i < 4; ++i)
          zp[m][i] = fmaxf(acc2[m][i], 0.f);
    } else if (s == 1) {                // |zp1 - zp2|
#pragma unroll
      for (int m = 0; m < 4; ++m)
#pragma unroll
        for (int i = 0; i < 4; ++i)
          zp[m][i] = fabsf(zp[m][i] - fmaxf(acc2[m][i], 0.f));
    } else {                            // q: combine + W5 dot immediately
      const float w5c = W5[wave * 16 + l15];
#pragma unroll
      for (int m = 0; m < 4; ++m)
#pragma unroll
        for (int i = 0; i < 4; ++i) {
          float v = fmaxf(acc2[m][i], 0.f) * zp[m][i] * w5c;
          // reduce over the 16 cols held by l15 (within each quad group)
          v += __shfl_xor(v, 1);
          v += __shfl_xor(v, 2);
          v += __shfl_xor(v, 4);
          v += __shfl_xor(v, 8);
          if (l15 == 0) lsPart[wave][m * 16 + q * 4 + i] = v;
        }
    }
    // No barrier needed before next stream's lsA[0] prologue writes:
    // all waves are past the post-H __syncthreads (so past every lsA read),
    // lsA[0] is disjoint from lsH/lsPart, and the new writes are only read
    // after the next stream's own __syncthreads.
  }

  __syncthreads();
  if (tid < 64) {
    float sum = lsPart[0][tid] + lsPart[1][tid] + lsPart[2][tid] + lsPart[3][tid]
              + lsPart[4][tid] + lsPart[5][tid] + lsPart[6][tid] + lsPart[7][tid];
    out[(size_t)blk * 64 + tid] = tanhf(fmaxf(sum, 0.f));
  }
}

extern "C" void kernel_launch(void* const* d_in, const int* in_sizes, int n_in,
                              void* d_out, int out_size, void* d_ws, size_t ws_size,
                              hipStream_t stream) {
  const float* X  = (const float*)d_in[0];
  const float* W1 = (const float*)d_in[1];
  const float* W2 = (const float*)d_in[2];
  const float* W3 = (const float*)d_in[3];
  const float* W4 = (const float*)d_in[4];
  const float* W5 = (const float*)d_in[5];
  float* out = (float*)d_out;
  unsigned short* ws = (unsigned short*)d_ws;  // needs 1.75 MB

  prep_weights<<<dim3(768), dim3(256), 0, stream>>>(W1, W2, W3, W4, ws);
  catsc_main<<<dim3(1024), dim3(512), 0, stream>>>(X, ws, W5, out);
}

// Round 3
// 1032.437 us; speedup vs baseline: 1.1699x; 1.0285x over previous
//
#include <hip/hip_runtime.h>

// CATSCluster: fused 3-stream MLP (768->256->128) + combine on MI355X.
// Round N+3: register diet to kill the persistent spills (round 2:
// VGPR_Count=64 + 92MB scratch writes under the (512,4) 128-reg cap).
//  - B-fragments loaded n-major: one (Bh,Bl) pair (8 regs) live at a time
//    instead of 16; per-acc MFMA order unchanged -> bitwise-identical.
//  - stream loop rolled (#pragma unroll 1): kills cross-stream live-range
//    extension from the x3 unroll.
//  - lane-invariant address parts hoisted; lo-plane reached via constant
//    +196608/+32768 offset (one pointer per weight matrix).
// Structure unchanged from round 2: K=64 intervals (12/stream), LDS
// double-buffer, depth-1 reg prefetch, T14 cross-stream prefetch,
// 512 threads, 2 blocks/CU.

typedef short short8 __attribute__((ext_vector_type(8)));   // 8 x bf16 (4 VGPRs)
typedef float f32x4 __attribute__((ext_vector_type(4)));    // MFMA accumulator

// d_ws layout (in unsigned short elements)
#define W1H_OFF 0u
#define W1L_OFF 196608u
#define W3H_OFF 393216u
#define W3L_OFF 589824u
#define W2H_OFF 786432u
#define W2L_OFF 819200u
#define W4H_OFF 851968u
#define W4L_OFF 884736u
// lo plane = hi plane + 196608 (W1/W3) or + 32768 (W2/W4)

__device__ __forceinline__ unsigned short bf16_rne(float f) {
  unsigned int u = __float_as_uint(f);
  u += 0x7FFFu + ((u >> 16) & 1u);      // round-to-nearest-even
  return (unsigned short)(u >> 16);
}

__device__ __forceinline__ void split_bf16(float f, unsigned short& h, unsigned short& l) {
  h = bf16_rne(f);
  float fh = __uint_as_float(((unsigned int)h) << 16);
  l = bf16_rne(f - fh);                 // residual; |x - hi - lo| ~ 2^-18 |x|
}

__device__ __forceinline__ void pack_split4(const float4 v, uint2& ph, uint2& pl) {
  unsigned short h0,h1,h2,h3,l0,l1,l2,l3;
  split_bf16(v.x,h0,l0); split_bf16(v.y,h1,l1);
  split_bf16(v.z,h2,l2); split_bf16(v.w,h3,l3);
  ph.x = (unsigned)h0 | ((unsigned)h1 << 16); ph.y = (unsigned)h2 | ((unsigned)h3 << 16);
  pl.x = (unsigned)l0 | ((unsigned)l1 << 16); pl.y = (unsigned)l2 | ((unsigned)l3 << 16);
}

__global__ __launch_bounds__(256) void prep_weights(
    const float* __restrict__ W1, const float* __restrict__ W2,
    const float* __restrict__ W3, const float* __restrict__ W4,
    unsigned short* __restrict__ ws)
{
  int i = blockIdx.x * 256 + threadIdx.x;
  if (i < 196608) {
    unsigned short h, l;
    split_bf16(W1[i], h, l); ws[W1H_OFF + i] = h; ws[W1L_OFF + i] = l;
    split_bf16(W3[i], h, l); ws[W3H_OFF + i] = h; ws[W3L_OFF + i] = l;
    if (i < 32768) {
      split_bf16(W2[i], h, l); ws[W2H_OFF + i] = h; ws[W2L_OFF + i] = l;
      split_bf16(W4[i], h, l); ws[W4H_OFF + i] = h; ws[W4L_OFF + i] = l;
    }
  }
}

#define STRIDE_A 72    // shorts per A-row in LDS (64 used; 144B stride, 16B-aligned)
#define STRIDE_H 264   // shorts per H-row in LDS (256 used; 528B stride, 16B-aligned)

__global__ __launch_bounds__(512, 4) void catsc_main(
    const float* __restrict__ X, const unsigned short* __restrict__ ws,
    const float* __restrict__ W5, float* __restrict__ out)
{
  __shared__ short lsA[2][2][64 * STRIDE_A]; // [dbuf][hi/lo][row*72+k]  36,864 B
  __shared__ short lsH[64 * STRIDE_H];       // relu(h) as bf16          33,792 B
  __shared__ float lsPart[8][64];            // cross-wave dot partials   2,048 B
                                             // total 72,704 B -> 2 blocks/CU

  const int tid  = threadIdx.x;
  const int wave = tid >> 6;      // 0..7
  const int lane = tid & 63;
  const int l15  = lane & 15;
  const int q    = lane >> 4;     // quad index 0..3
  const int blk  = blockIdx.x;    // 0..1023, 64 rows each; 64 blocks per n (4096/64)

  // X_data is (16, 4097, 2304); skip row 0 of each n.
  const float* Xb = X + (size_t)((blk >> 6) * 4097 + 1 + ((blk & 63) << 6)) * 2304;

  // cooperative staging coords: thread -> (row, 8-float segment); 512 thr cover 64x64/interval
  const int srow = tid >> 3;        // 0..63
  const int scol = (tid & 7) << 3;  // float offset 0,8,...,56 within 64-col interval
  const float* Xs = Xb + (size_t)srow * 2304 + scol;
  short* lsW = &lsA[0][0][0];       // raw base for staging writes
  const int sidx = srow * STRIDE_A + scol;   // short index within one lsA plane
  const int PLANE = 64 * STRIDE_A;           // shorts per [hi/lo] plane

  // hoisted lane-invariant offsets
  const int arow = l15 * STRIDE_A + q * 8;                   // A-frag LDS offset
  const size_t bwl = (size_t)(wave * 32 + l15) * 768 + q * 8; // B1 lane/wave base
  const size_t cwl = (size_t)(wave * 16 + l15) * 256 + q * 8; // B2 lane/wave base
  const int hrow = l15 * STRIDE_H + q * 8;                   // H-frag LDS offset

  f32x4 zp[4];   // after p1: zp1 ; after p2: |zp1 - zp2| ; consumed by q-combine

  // T14: interval-0 X data for stream 0 (p1, cols 768..) issued at kernel top
  float4 vP0 = *(const float4*)(Xs + 768);
  float4 vP1 = *(const float4*)(Xs + 768 + 4);

#pragma unroll 1
  for (int s = 0; s < 3; ++s) {
    // stream order: s=0 -> p1 (768..), s=1 -> p2 (1536..), s=2 -> q (0..)
    const int so = (s == 0) ? 768 : (s == 1) ? 1536 : 0;
    const unsigned short* B1h = ws + (s == 2 ? W3H_OFF : W1H_OFF) + bwl;
    const unsigned short* B2h = ws + (s == 2 ? W4H_OFF : W2H_OFF) + cwl;

    f32x4 acc[4][2];
#pragma unroll
    for (int m = 0; m < 4; ++m)
#pragma unroll
      for (int n = 0; n < 2; ++n)
        acc[m][n] = f32x4{0.f, 0.f, 0.f, 0.f};

    // ---- prologue: stage interval 0 (from the early-issued vP regs) ----
    {
      uint2 ph, pl;
      pack_split4(vP0, ph, pl);
      *(uint2*)&lsW[sidx]         = ph;
      *(uint2*)&lsW[PLANE + sidx] = pl;
      pack_split4(vP1, ph, pl);
      *(uint2*)&lsW[sidx + 4]         = ph;
      *(uint2*)&lsW[PLANE + sidx + 4] = pl;
    }
    __syncthreads();

    // ---- GEMM1: 12 intervals of K=64, double-buffered, depth-1 prefetch ----
    for (int p = 0; p < 12; ++p) {
      const int b = p & 1;
      // issue X loads for interval p+1 now; consumed at end of this interval
      float4 vB0, vB1;
      if (p + 1 < 12) {
        vB0 = *(const float4*)(Xs + so + (p + 1) * 64);
        vB1 = *(const float4*)(Xs + so + (p + 1) * 64 + 4);
      }
      const short* As0 = &lsA[b][0][arow];
      const short* As1 = &lsA[b][1][arow];

#pragma unroll
      for (int sub = 0; sub < 2; ++sub) {
#pragma unroll
        for (int mh = 0; mh < 2; ++mh) {
          // A fragments in m-pairs (16 regs live)
          short8 Ah[2], Al[2];
#pragma unroll
          for (int mm = 0; mm < 2; ++mm) {
            const int a = (mh * 2 + mm) * 16 * STRIDE_A + sub * 32;
            Ah[mm] = *(const short8*)(As0 + a);
            Al[mm] = *(const short8*)(As1 + a);
          }
          // B n-major: one (Bh,Bl) pair (8 regs) live at a time.
          // per-acc order: Ah*Bh, Ah*Bl, Al*Bh -- identical to before.
#pragma unroll
          for (int n = 0; n < 2; ++n) {
            const unsigned short* bp = B1h + (size_t)n * 12288 + p * 64 + sub * 32;
            short8 Bh = *(const short8*)bp;
            short8 Bl = *(const short8*)(bp + 196608);
            acc[mh*2+0][n] = __builtin_amdgcn_mfma_f32_16x16x32_bf16(Ah[0], Bh, acc[mh*2+0][n], 0, 0, 0);
            acc[mh*2+1][n] = __builtin_amdgcn_mfma_f32_16x16x32_bf16(Ah[1], Bh, acc[mh*2+1][n], 0, 0, 0);
            acc[mh*2+0][n] = __builtin_amdgcn_mfma_f32_16x16x32_bf16(Ah[0], Bl, acc[mh*2+0][n], 0, 0, 0);
            acc[mh*2+1][n] = __builtin_amdgcn_mfma_f32_16x16x32_bf16(Ah[1], Bl, acc[mh*2+1][n], 0, 0, 0);
            acc[mh*2+0][n] = __builtin_amdgcn_mfma_f32_16x16x32_bf16(Al[0], Bh, acc[mh*2+0][n], 0, 0, 0);
            acc[mh*2+1][n] = __builtin_amdgcn_mfma_f32_16x16x32_bf16(Al[1], Bh, acc[mh*2+1][n], 0, 0, 0);
          }
        }
      }

      // split the prefetched interval p+1 into the other LDS buffer
      if (p + 1 < 12) {
        short* dst = lsW + (b ^ 1) * (2 * PLANE);
        uint2 ph, pl;
        pack_split4(vB0, ph, pl);
        *(uint2*)&dst[sidx]         = ph;
        *(uint2*)&dst[PLANE + sidx] = pl;
        pack_split4(vB1, ph, pl);
        *(uint2*)&dst[sidx + 4]         = ph;
        *(uint2*)&dst[PLANE + sidx + 4] = pl;
      }
      __syncthreads();
    }

    // ---- H = relu(acc) -> LDS as bf16 (C-layout: col=l15, row=q*4+i) ----
#pragma unroll
    for (int m = 0; m < 4; ++m)
#pragma unroll
      for (int n = 0; n < 2; ++n) {
        int col = (wave * 2 + n) * 16 + l15;
#pragma unroll
        for (int i = 0; i < 4; ++i) {
          int row = m * 16 + q * 4 + i;
          lsH[row * STRIDE_H + col] = bf16_rne(fmaxf(acc[m][n][i], 0.f));
        }
      }
    __syncthreads();

    // T14: issue next stream's interval-0 X loads now; consumed after GEMM2
    if (s < 2) {
      const int nso = (s == 0) ? 1536 : 0;
      vP0 = *(const float4*)(Xs + nso);
      vP1 = *(const float4*)(Xs + nso + 4);
    }

    // ---- GEMM2: (64 x 256) x (256 -> 128), H bf16 x W split (2 terms);
    //      8 waves x 16 output cols each ----
    f32x4 acc2[4];
#pragma unroll
    for (int m = 0; m < 4; ++m) acc2[m] = f32x4{0.f, 0.f, 0.f, 0.f};

    for (int c2 = 0; c2 < 8; ++c2) {
      const unsigned short* cp = B2h + c2 * 32;
      short8 Ch = *(const short8*)cp;
      short8 Cl = *(const short8*)(cp + 32768);
      short8 Ha[4];
#pragma unroll
      for (int m = 0; m < 4; ++m)
        Ha[m] = *(const short8*)&lsH[m * 16 * STRIDE_H + hrow + c2 * 32];
#pragma unroll
      for (int m = 0; m < 4; ++m)
        acc2[m] = __builtin_amdgcn_mfma_f32_16x16x32_bf16(Ha[m], Ch, acc2[m], 0, 0, 0);
#pragma unroll
      for (int m = 0; m < 4; ++m)
        acc2[m] = __builtin_amdgcn_mfma_f32_16x16x32_bf16(Ha[m], Cl, acc2[m], 0, 0, 0);
    }

    // ---- per-stream epilogue: minimal cross-stream register state ----
    if (s == 0) {                       // zp1
#pragma unroll
      for (int m = 0; m < 4; ++m)
#pragma unroll
        for (int i = 0; i < 4; ++i)
          zp[m][i] = fmaxf(acc2[m][i], 0.f);
    } else if (s == 1) {                // |zp1 - zp2|
#pragma unroll
      for (int m = 0; m < 4; ++m)
#pragma unroll
        for (int i = 0; i < 4; ++i)
          zp[m][i] = fabsf(zp[m][i] - fmaxf(acc2[m][i], 0.f));
    } else {                            // q: combine + W5 dot immediately
      const float w5c = W5[wave * 16 + l15];
#pragma unroll
      for (int m = 0; m < 4; ++m)
#pragma unroll
        for (int i = 0; i < 4; ++i) {
          float v = fmaxf(acc2[m][i], 0.f) * zp[m][i] * w5c;
          // reduce over the 16 cols held by l15 (within each quad group)
          v += __shfl_xor(v, 1);
          v += __shfl_xor(v, 2);
          v += __shfl_xor(v, 4);
          v += __shfl_xor(v, 8);
          if (l15 == 0) lsPart[wave][m * 16 + q * 4 + i] = v;
        }
    }
    // No barrier needed before next stream's lsA prologue writes: every wave
    // is past the post-H __syncthreads (so past all lsA reads of this
    // stream); prologue touches lsA only, GEMM2 reads lsH only (disjoint),
    // and new lsA data is only read after the next stream's own barrier.
  }

  __syncthreads();
  if (tid < 64) {
    float sum = lsPart[0][tid] + lsPart[1][tid] + lsPart[2][tid] + lsPart[3][tid]
              + lsPart[4][tid] + lsPart[5][tid] + lsPart[6][tid] + lsPart[7][tid];
    out[(size_t)blk * 64 + tid] = tanhf(fmaxf(sum, 0.f));
  }
}

extern "C" void kernel_launch(void* const* d_in, const int* in_sizes, int n_in,
                              void* d_out, int out_size, void* d_ws, size_t ws_size,
                              hipStream_t stream) {
  const float* X  = (const float*)d_in[0];
  const float* W1 = (const float*)d_in[1];
  const float* W2 = (const float*)d_in[2];
  const float* W3 = (const float*)d_in[3];
  const float* W4 = (const float*)d_in[4];
  const float* W5 = (const float*)d_in[5];
  float* out = (float*)d_out;
  unsigned short* ws = (unsigned short*)d_ws;  // needs 1.75 MB

  prep_weights<<<dim3(768), dim3(256), 0, stream>>>(W1, W2, W3, W4, ws);
  catsc_main<<<dim3(1024), dim3(512), 0, stream>>>(X, ws, W5, out);
}